// Round 1
// baseline (640.253 us; speedup 1.0000x reference)
//
#include <hip/hip_runtime.h>

#define N_NODES 50000
#define N_EDGES 800000
// msg MLP: in 192 (=[x_i|x_j|id_i|id_j]), hidden 192, out 64
// upd MLP: in 128 (=[x*nc | agg]), hidden 192, out 128

// ---------------------------------------------------------------------------
// Kernel P: per-node partial first-layer activations for the message MLP.
// P1[n][h] = sum_k [x|id][n][k] * W1[target_row(k)][h] + b1[h]   (target contribution, b1 folded)
// P2[n][h] = sum_k [x|id][n][k] * W1[source_row(k)][h]           (source contribution)
// W1 rows: 0..63 x_i, 64..127 x_j, 128..159 id_i, 160..191 id_j
// ---------------------------------------------------------------------------
__global__ __launch_bounds__(384) void k_pre(const float* __restrict__ x,
                                             const float* __restrict__ ids,
                                             const float* __restrict__ W1,
                                             const float* __restrict__ b1,
                                             float* __restrict__ P1,
                                             float* __restrict__ P2) {
    __shared__ float xidT[96][8];  // [k][node]  (transposed for float4 broadcast reads)
    const int t = threadIdx.x;
    const int part = t / 192;  // 0 -> P1 (target rows), 1 -> P2 (source rows)
    const int h = t % 192;
    const int n0 = blockIdx.x * 8;

    for (int v = t; v < 8 * 96; v += 384) {
        const int nn = v / 96, c = v % 96;
        const int node = n0 + nn;
        float val = 0.f;
        if (node < N_NODES)
            val = (c < 64) ? x[node * 64 + c] : ids[node * 32 + (c - 64)];
        xidT[c][nn] = val;
    }
    __syncthreads();

    float acc[8];
    const float binit = (part == 0) ? b1[h] : 0.f;
#pragma unroll
    for (int nn = 0; nn < 8; ++nn) acc[nn] = binit;

    for (int k = 0; k < 96; ++k) {
        const int row = (k < 64) ? (part ? k + 64 : k) : (part ? k + 96 : k + 64);
        const float w = W1[row * 192 + h];
        const float4 a = *(const float4*)&xidT[k][0];
        const float4 b = *(const float4*)&xidT[k][4];
        acc[0] += a.x * w; acc[1] += a.y * w; acc[2] += a.z * w; acc[3] += a.w * w;
        acc[4] += b.x * w; acc[5] += b.y * w; acc[6] += b.z * w; acc[7] += b.w * w;
    }

    float* __restrict__ dst = part ? P2 : P1;
#pragma unroll
    for (int nn = 0; nn < 8; ++nn) {
        const int node = n0 + nn;
        if (node < N_NODES) dst[node * 192 + h] = acc[nn];
    }
}

// ---------------------------------------------------------------------------
// Kernel E: per-edge second layer + scatter.
// h[k] = ReLU(P1[i][k] + P2[j][k]);  msg[m] = (sum_k h[k]*W2[k][m] + b2[m]) * ec[e]
// agg[i][m] += msg[m]   (atomic)
// One wave handles 8 edges at a time; W2 staged in LDS; lane = output m (0..63).
// ---------------------------------------------------------------------------
#define EPW 8
__global__ __launch_bounds__(256) void k_edge(const int* __restrict__ ei,
                                              const float* __restrict__ ec,
                                              const float* __restrict__ P1,
                                              const float* __restrict__ P2,
                                              const float* __restrict__ W2,
                                              const float* __restrict__ b2,
                                              float* __restrict__ agg) {
    __shared__ float w2s[192 * 64];      // 48 KB
    __shared__ float hT[4][192][EPW];    // 24 KB  [wave][k][edge]
    const int t = threadIdx.x;
    for (int v = t; v < 192 * 64; v += 256) w2s[v] = W2[v];
    __syncthreads();

    const int w = t >> 6, lane = t & 63;
    const float b2v = b2[lane];
    const int nGroups = N_EDGES / EPW;  // 100000 (exact)
    const int gstride = gridDim.x * 4;

    for (int g = blockIdx.x * 4 + w; g < nGroups; g += gstride) {
        const int e0 = g * EPW;
        int iAry[EPW], jAry[EPW];
#pragma unroll
        for (int e = 0; e < EPW; ++e) {
            jAry[e] = ei[e0 + e];            // source j
            iAry[e] = ei[N_EDGES + e0 + e];  // target i
        }
        // h for 8 edges, transposed into LDS (wave-private, no block barrier needed)
#pragma unroll
        for (int c = 0; c < 3; ++c) {
            const int k = lane + 64 * c;
            float hv[EPW];
#pragma unroll
            for (int e = 0; e < EPW; ++e) {
                const float s = P1[iAry[e] * 192 + k] + P2[jAry[e] * 192 + k];
                hv[e] = s > 0.f ? s : 0.f;
            }
            *(float4*)&hT[w][k][0] = *(const float4*)&hv[0];
            *(float4*)&hT[w][k][4] = *(const float4*)&hv[4];
        }

        float acc[EPW];
#pragma unroll
        for (int e = 0; e < EPW; ++e) acc[e] = 0.f;
#pragma unroll 4
        for (int k = 0; k < 192; ++k) {
            const float wv = w2s[k * 64 + lane];
            const float4 h0 = *(const float4*)&hT[w][k][0];
            const float4 h1 = *(const float4*)&hT[w][k][4];
            acc[0] += h0.x * wv; acc[1] += h0.y * wv;
            acc[2] += h0.z * wv; acc[3] += h0.w * wv;
            acc[4] += h1.x * wv; acc[5] += h1.y * wv;
            acc[6] += h1.z * wv; acc[7] += h1.w * wv;
        }
#pragma unroll
        for (int e = 0; e < EPW; ++e) {
            const float val = (acc[e] + b2v) * ec[e0 + e];
            atomicAdd(&agg[iAry[e] * 64 + lane], val);
        }
    }
}

// ---------------------------------------------------------------------------
// Kernel U1: H = ReLU([x*nc | agg] @ uW1 + ub1)   [N,192]
// ---------------------------------------------------------------------------
__global__ __launch_bounds__(192) void k_upd1(const float* __restrict__ x,
                                              const float* __restrict__ nc,
                                              const float* __restrict__ agg,
                                              const float* __restrict__ W1,
                                              const float* __restrict__ b1,
                                              float* __restrict__ H) {
    __shared__ float uT[128][16];  // [k][node]
    const int t = threadIdx.x;
    const int n0 = blockIdx.x * 16;
    for (int v = t; v < 128 * 16; v += 192) {
        const int k = v >> 4, nn = v & 15;
        const int node = n0 + nn;
        float val = 0.f;
        if (node < N_NODES)
            val = (k < 64) ? x[node * 64 + k] * nc[node] : agg[node * 64 + (k - 64)];
        uT[k][nn] = val;
    }
    __syncthreads();

    const int h = t;
    float acc[16];
    const float bv = b1[h];
#pragma unroll
    for (int nn = 0; nn < 16; ++nn) acc[nn] = bv;
    for (int k = 0; k < 128; ++k) {
        const float wv = W1[k * 192 + h];
        const float4* uv = (const float4*)&uT[k][0];
#pragma unroll
        for (int q = 0; q < 4; ++q) {
            const float4 u4 = uv[q];
            acc[q * 4 + 0] += u4.x * wv; acc[q * 4 + 1] += u4.y * wv;
            acc[q * 4 + 2] += u4.z * wv; acc[q * 4 + 3] += u4.w * wv;
        }
    }
#pragma unroll
    for (int nn = 0; nn < 16; ++nn) {
        const int node = n0 + nn;
        if (node < N_NODES) H[node * 192 + h] = acc[nn] > 0.f ? acc[nn] : 0.f;
    }
}

// ---------------------------------------------------------------------------
// Kernel U2: out = H @ uW2 + ub2   [N,128]
// ---------------------------------------------------------------------------
__global__ __launch_bounds__(128) void k_upd2(const float* __restrict__ H,
                                              const float* __restrict__ W2,
                                              const float* __restrict__ b2,
                                              float* __restrict__ out) {
    __shared__ float hT[192][16];  // [k][node]
    const int t = threadIdx.x;
    const int n0 = blockIdx.x * 16;
    for (int v = t; v < 192 * 16; v += 128) {
        const int k = v >> 4, nn = v & 15;
        const int node = n0 + nn;
        hT[k][nn] = (node < N_NODES) ? H[node * 192 + k] : 0.f;
    }
    __syncthreads();

    const int o = t;
    float acc[16];
    const float bv = b2[o];
#pragma unroll
    for (int nn = 0; nn < 16; ++nn) acc[nn] = bv;
    for (int k = 0; k < 192; ++k) {
        const float wv = W2[k * 128 + o];
        const float4* hv4 = (const float4*)&hT[k][0];
#pragma unroll
        for (int q = 0; q < 4; ++q) {
            const float4 h4 = hv4[q];
            acc[q * 4 + 0] += h4.x * wv; acc[q * 4 + 1] += h4.y * wv;
            acc[q * 4 + 2] += h4.z * wv; acc[q * 4 + 3] += h4.w * wv;
        }
    }
#pragma unroll
    for (int nn = 0; nn < 16; ++nn) {
        const int node = n0 + nn;
        if (node < N_NODES) out[node * 128 + o] = acc[nn];
    }
}

extern "C" void kernel_launch(void* const* d_in, const int* in_sizes, int n_in,
                              void* d_out, int out_size, void* d_ws, size_t ws_size,
                              hipStream_t stream) {
    const float* x   = (const float*)d_in[0];
    const int*   ei  = (const int*)d_in[1];
    const float* ncv = (const float*)d_in[2];
    const float* ecv = (const float*)d_in[3];
    const float* ids = (const float*)d_in[4];
    // d_in[5] degrees: unused by the reference
    const float* mW1 = (const float*)d_in[6];
    const float* mb1 = (const float*)d_in[7];
    const float* mW2 = (const float*)d_in[8];
    const float* mb2 = (const float*)d_in[9];
    const float* uW1 = (const float*)d_in[10];
    const float* ub1 = (const float*)d_in[11];
    const float* uW2 = (const float*)d_in[12];
    const float* ub2 = (const float*)d_in[13];
    float* out = (float*)d_out;

    char* ws = (char*)d_ws;
    float* P1  = (float*)ws;                        // 50000*192 f32 = 38.4 MB
    float* P2  = P1 + (size_t)N_NODES * 192;        // 38.4 MB
    float* agg = P2 + (size_t)N_NODES * 192;        // 50000*64 f32 = 12.8 MB
    float* H   = P1;                                // reuse P1 region after k_edge

    hipMemsetAsync(agg, 0, (size_t)N_NODES * 64 * sizeof(float), stream);
    k_pre<<<N_NODES / 8, 384, 0, stream>>>(x, ids, mW1, mb1, P1, P2);
    k_edge<<<512, 256, 0, stream>>>(ei, ecv, P1, P2, mW2, mb2, agg);
    k_upd1<<<(N_NODES + 15) / 16, 192, 0, stream>>>(x, ncv, agg, uW1, ub1, H);
    k_upd2<<<(N_NODES + 15) / 16, 128, 0, stream>>>(H, uW2, ub2, out);
}

// Round 2
// 394.062 us; speedup vs baseline: 1.6248x; 1.6248x over previous
//
#include <hip/hip_runtime.h>
#include <hip/hip_bf16.h>

#define N_NODES 50000
#define N_EDGES 800000

typedef __attribute__((ext_vector_type(8))) short short8;
typedef __attribute__((ext_vector_type(4))) float f32x4;

static __device__ inline unsigned short f2bf_bits(float f) {
    union { __hip_bfloat16 b; unsigned short s; } c;
    c.b = __float2bfloat16(f);
    return c.s;
}
static __device__ inline float bflo(unsigned u) {
    union { unsigned v; float f; } c; c.v = u << 16; return c.f;
}
static __device__ inline float bfhi(unsigned u) {
    union { unsigned v; float f; } c; c.v = u & 0xffff0000u; return c.f;
}

// ---------------------------------------------------------------------------
// Kernel P: per-node partial first-layer activations for the message MLP.
// P1[n][h] = [x|id][n] . W1[target rows] + b1   (bf16 out)
// P2[n][h] = [x|id][n] . W1[source rows]        (bf16 out)
// W1 rows: 0..63 x_i, 64..127 x_j, 128..159 id_i, 160..191 id_j
// ---------------------------------------------------------------------------
__global__ __launch_bounds__(384) void k_pre(const float* __restrict__ x,
                                             const float* __restrict__ ids,
                                             const float* __restrict__ W1,
                                             const float* __restrict__ b1,
                                             __hip_bfloat16* __restrict__ P1,
                                             __hip_bfloat16* __restrict__ P2) {
    __shared__ float xidT[96][8];  // [k][node]
    const int t = threadIdx.x;
    const int part = t / 192;  // 0 -> P1 (target rows), 1 -> P2 (source rows)
    const int h = t % 192;
    const int n0 = blockIdx.x * 8;

    for (int v = t; v < 8 * 96; v += 384) {
        const int nn = v / 96, c = v % 96;
        const int node = n0 + nn;
        float val = 0.f;
        if (node < N_NODES)
            val = (c < 64) ? x[node * 64 + c] : ids[node * 32 + (c - 64)];
        xidT[c][nn] = val;
    }
    __syncthreads();

    float acc[8];
    const float binit = (part == 0) ? b1[h] : 0.f;
#pragma unroll
    for (int nn = 0; nn < 8; ++nn) acc[nn] = binit;

    for (int k = 0; k < 96; ++k) {
        const int row = (k < 64) ? (part ? k + 64 : k) : (part ? k + 96 : k + 64);
        const float w = W1[row * 192 + h];
        const float4 a = *(const float4*)&xidT[k][0];
        const float4 b = *(const float4*)&xidT[k][4];
        acc[0] += a.x * w; acc[1] += a.y * w; acc[2] += a.z * w; acc[3] += a.w * w;
        acc[4] += b.x * w; acc[5] += b.y * w; acc[6] += b.z * w; acc[7] += b.w * w;
    }

    __hip_bfloat16* __restrict__ dst = part ? P2 : P1;
#pragma unroll
    for (int nn = 0; nn < 8; ++nn) {
        const int node = n0 + nn;
        if (node < N_NODES) dst[node * 192 + h] = __float2bfloat16(acc[nn]);
    }
}

// ---------------------------------------------------------------------------
// Kernel E (MFMA): per-edge second layer + scatter.
// Per wave-iteration: 16 edges. A = ReLU(P1[i]+P2[j]) gathered straight into
// the mfma_f32_16x16x32_bf16 A-fragment layout (lane l: edge=l&15,
// k = (l>>4)*8 + i + 32*t). B = W2 bf16, prebuilt in registers (24 frags).
// D layout (m89): col = lane&15 (out), row = (lane>>4)*4 + reg (edge).
// ---------------------------------------------------------------------------
__global__ __launch_bounds__(256) void k_edge(const int* __restrict__ ei,
                                              const float* __restrict__ ec,
                                              const __hip_bfloat16* __restrict__ P1,
                                              const __hip_bfloat16* __restrict__ P2,
                                              const float* __restrict__ W2,
                                              const float* __restrict__ b2,
                                              float* __restrict__ agg) {
    const int t = threadIdx.x;
    const int w = t >> 6;
    const int l = t & 63;
    const int e = l & 15;        // edge-within-group for A; out-col for C/D
    const int kg = l >> 4;       // k-group

    // --- Prologue: B fragments for W2 (192x64), held in registers. ---
    short8 Bf[6][4];
#pragma unroll
    for (int tt = 0; tt < 6; ++tt) {
#pragma unroll
        for (int n = 0; n < 4; ++n) {
            short8 v;
#pragma unroll
            for (int i = 0; i < 8; ++i)
                v[i] = (short)f2bf_bits(W2[(tt * 32 + kg * 8 + i) * 64 + n * 16 + e]);
            Bf[tt][n] = v;
        }
    }
    float b2v[4];
#pragma unroll
    for (int n = 0; n < 4; ++n) b2v[n] = b2[n * 16 + e];

    const int nGroups = N_EDGES / 16;  // 50000
    const int wstride = gridDim.x * 4;

    for (int g = blockIdx.x * 4 + w; g < nGroups; g += wstride) {
        const int e0 = g * 16;
        const int jj = ei[e0 + e];            // source j
        const int ii = ei[N_EDGES + e0 + e];  // target i
        const __hip_bfloat16* r1 = P1 + (size_t)ii * 192 + kg * 8;
        const __hip_bfloat16* r2 = P2 + (size_t)jj * 192 + kg * 8;

        f32x4 acc0 = {0.f, 0.f, 0.f, 0.f};
        f32x4 acc1 = {0.f, 0.f, 0.f, 0.f};
        f32x4 acc2 = {0.f, 0.f, 0.f, 0.f};
        f32x4 acc3 = {0.f, 0.f, 0.f, 0.f};

#pragma unroll
        for (int tt = 0; tt < 6; ++tt) {
            union { uint4 q; unsigned u[4]; } A1, A2;
            A1.q = *(const uint4*)(r1 + tt * 32);
            A2.q = *(const uint4*)(r2 + tt * 32);
            short8 h;
#pragma unroll
            for (int p = 0; p < 4; ++p) {
                float s0 = bflo(A1.u[p]) + bflo(A2.u[p]);
                float s1 = bfhi(A1.u[p]) + bfhi(A2.u[p]);
                s0 = s0 > 0.f ? s0 : 0.f;
                s1 = s1 > 0.f ? s1 : 0.f;
                h[2 * p]     = (short)f2bf_bits(s0);
                h[2 * p + 1] = (short)f2bf_bits(s1);
            }
            acc0 = __builtin_amdgcn_mfma_f32_16x16x32_bf16(h, Bf[tt][0], acc0, 0, 0, 0);
            acc1 = __builtin_amdgcn_mfma_f32_16x16x32_bf16(h, Bf[tt][1], acc1, 0, 0, 0);
            acc2 = __builtin_amdgcn_mfma_f32_16x16x32_bf16(h, Bf[tt][2], acc2, 0, 0, 0);
            acc3 = __builtin_amdgcn_mfma_f32_16x16x32_bf16(h, Bf[tt][3], acc3, 0, 0, 0);
        }

        // epilogue: edge(row) = kg*4 + r, out-col = n*16 + e
        const float4 ecq = *(const float4*)(ec + e0 + kg * 4);
#pragma unroll
        for (int r = 0; r < 4; ++r) {
            const int edge = kg * 4 + r;
            const int it = __shfl(ii, edge);  // lane 'edge' (0..15) holds target idx
            const float ecv = ((const float*)&ecq)[r];
            float v0 = (acc0[r] + b2v[0]) * ecv;
            float v1 = (acc1[r] + b2v[1]) * ecv;
            float v2 = (acc2[r] + b2v[2]) * ecv;
            float v3 = (acc3[r] + b2v[3]) * ecv;
            float* base = agg + (size_t)it * 64 + e;
            atomicAdd(base,      v0);
            atomicAdd(base + 16, v1);
            atomicAdd(base + 32, v2);
            atomicAdd(base + 48, v3);
        }
    }
}

// ---------------------------------------------------------------------------
// Kernel U1: H = ReLU([x*nc | agg] @ uW1 + ub1)   [N,192]
// ---------------------------------------------------------------------------
__global__ __launch_bounds__(192) void k_upd1(const float* __restrict__ x,
                                              const float* __restrict__ nc,
                                              const float* __restrict__ agg,
                                              const float* __restrict__ W1,
                                              const float* __restrict__ b1,
                                              float* __restrict__ H) {
    __shared__ float uT[128][16];  // [k][node]
    const int t = threadIdx.x;
    const int n0 = blockIdx.x * 16;
    for (int v = t; v < 128 * 16; v += 192) {
        const int k = v >> 4, nn = v & 15;
        const int node = n0 + nn;
        float val = 0.f;
        if (node < N_NODES)
            val = (k < 64) ? x[node * 64 + k] * nc[node] : agg[node * 64 + (k - 64)];
        uT[k][nn] = val;
    }
    __syncthreads();

    const int h = t;
    float acc[16];
    const float bv = b1[h];
#pragma unroll
    for (int nn = 0; nn < 16; ++nn) acc[nn] = bv;
    for (int k = 0; k < 128; ++k) {
        const float wv = W1[k * 192 + h];
        const float4* uv = (const float4*)&uT[k][0];
#pragma unroll
        for (int q = 0; q < 4; ++q) {
            const float4 u4 = uv[q];
            acc[q * 4 + 0] += u4.x * wv; acc[q * 4 + 1] += u4.y * wv;
            acc[q * 4 + 2] += u4.z * wv; acc[q * 4 + 3] += u4.w * wv;
        }
    }
#pragma unroll
    for (int nn = 0; nn < 16; ++nn) {
        const int node = n0 + nn;
        if (node < N_NODES) H[node * 192 + h] = acc[nn] > 0.f ? acc[nn] : 0.f;
    }
}

// ---------------------------------------------------------------------------
// Kernel U2: out = H @ uW2 + ub2   [N,128]
// ---------------------------------------------------------------------------
__global__ __launch_bounds__(128) void k_upd2(const float* __restrict__ H,
                                              const float* __restrict__ W2,
                                              const float* __restrict__ b2,
                                              float* __restrict__ out) {
    __shared__ float hT[192][16];  // [k][node]
    const int t = threadIdx.x;
    const int n0 = blockIdx.x * 16;
    for (int v = t; v < 192 * 16; v += 128) {
        const int k = v >> 4, nn = v & 15;
        const int node = n0 + nn;
        hT[k][nn] = (node < N_NODES) ? H[node * 192 + k] : 0.f;
    }
    __syncthreads();

    const int o = t;
    float acc[16];
    const float bv = b2[o];
#pragma unroll
    for (int nn = 0; nn < 16; ++nn) acc[nn] = bv;
    for (int k = 0; k < 192; ++k) {
        const float wv = W2[k * 128 + o];
        const float4* hv4 = (const float4*)&hT[k][0];
#pragma unroll
        for (int q = 0; q < 4; ++q) {
            const float4 h4 = hv4[q];
            acc[q * 4 + 0] += h4.x * wv; acc[q * 4 + 1] += h4.y * wv;
            acc[q * 4 + 2] += h4.z * wv; acc[q * 4 + 3] += h4.w * wv;
        }
    }
#pragma unroll
    for (int nn = 0; nn < 16; ++nn) {
        const int node = n0 + nn;
        if (node < N_NODES) out[node * 128 + o] = acc[nn];
    }
}

extern "C" void kernel_launch(void* const* d_in, const int* in_sizes, int n_in,
                              void* d_out, int out_size, void* d_ws, size_t ws_size,
                              hipStream_t stream) {
    const float* x   = (const float*)d_in[0];
    const int*   ei  = (const int*)d_in[1];
    const float* ncv = (const float*)d_in[2];
    const float* ecv = (const float*)d_in[3];
    const float* ids = (const float*)d_in[4];
    // d_in[5] degrees: unused by the reference
    const float* mW1 = (const float*)d_in[6];
    const float* mb1 = (const float*)d_in[7];
    const float* mW2 = (const float*)d_in[8];
    const float* mb2 = (const float*)d_in[9];
    const float* uW1 = (const float*)d_in[10];
    const float* ub1 = (const float*)d_in[11];
    const float* uW2 = (const float*)d_in[12];
    const float* ub2 = (const float*)d_in[13];
    float* out = (float*)d_out;

    char* ws = (char*)d_ws;
    __hip_bfloat16* P1b = (__hip_bfloat16*)ws;            // 50000*192*2B = 19.2 MB
    __hip_bfloat16* P2b = P1b + (size_t)N_NODES * 192;    // 19.2 MB
    float* agg = (float*)(P2b + (size_t)N_NODES * 192);   // 50000*64*4B = 12.8 MB
    float* H   = agg + (size_t)N_NODES * 64;              // 50000*192*4B = 38.4 MB

    hipMemsetAsync(agg, 0, (size_t)N_NODES * 64 * sizeof(float), stream);
    k_pre<<<N_NODES / 8, 384, 0, stream>>>(x, ids, mW1, mb1, P1b, P2b);
    k_edge<<<1024, 256, 0, stream>>>(ei, ecv, P1b, P2b, mW2, mb2, agg);
    k_upd1<<<(N_NODES + 15) / 16, 192, 0, stream>>>(x, ncv, agg, uW1, ub1, H);
    k_upd2<<<(N_NODES + 15) / 16, 128, 0, stream>>>(H, uW2, ub2, out);
}

// Round 3
// 261.590 us; speedup vs baseline: 2.4475x; 1.5064x over previous
//
#include <hip/hip_runtime.h>
#include <hip/hip_bf16.h>

#define N_NODES 50000
#define N_EDGES 800000
#define NPAD    50048   // nodes padded to multiple of 64

typedef __attribute__((ext_vector_type(8))) short short8;
typedef __attribute__((ext_vector_type(4))) float f32x4;

static __device__ inline short f2bf(float f) {
    union { __hip_bfloat16 b; short s; } c; c.b = __float2bfloat16(f); return c.s;
}
static __device__ inline float bf2f(short s) {
    union { unsigned u; float f; } c; c.u = ((unsigned)(unsigned short)s) << 16; return c.f;
}
static __device__ inline float bflo(unsigned u) {
    union { unsigned v; float f; } c; c.v = u << 16; return c.f;
}
static __device__ inline float bfhi(unsigned u) {
    union { unsigned v; float f; } c; c.v = u & 0xffff0000u; return c.f;
}

// ---------------------------------------------------------------------------
// k_pack: bf16-ize inputs + prepack all weights into MFMA B-fragment order.
// Fragment layout (16x16x32): frag(kt,nt,lane)[i] = M[kt*32+(lane>>4)*8+i][nt*16+(lane&15)]
// stored contiguously as [...(kt*NT+nt)*64+lane ...][8].
// ---------------------------------------------------------------------------
__global__ __launch_bounds__(256) void k_pack(const float* __restrict__ x,
                                              const float* __restrict__ ids,
                                              const float* __restrict__ mW1,
                                              const float* __restrict__ mW2,
                                              const float* __restrict__ uW1,
                                              const float* __restrict__ uW2,
                                              __hip_bfloat16* __restrict__ Xid,
                                              __hip_bfloat16* __restrict__ W1pk,
                                              __hip_bfloat16* __restrict__ W2pk,
                                              __hip_bfloat16* __restrict__ uW1pk,
                                              __hip_bfloat16* __restrict__ uW2pk) {
    const int tid = blockIdx.x * 256 + threadIdx.x;
    const int XN = NPAD * 96 / 8;  // 600576 groups of 8
    if (tid < XN) {
        const int n = tid / 12, c0 = (tid % 12) * 8;
        short8 v;
#pragma unroll
        for (int i = 0; i < 8; ++i) {
            const int c = c0 + i;
            float f = 0.f;
            if (n < N_NODES) f = (c < 64) ? x[n * 64 + c] : ids[n * 32 + (c - 64)];
            v[i] = f2bf(f);
        }
        *(short8*)&Xid[n * 96 + c0] = v;
        return;
    }
    int r = tid - XN;
    // W1pk: msg-W1 rearranged, K=96, NT=24 (cols 0..191 -> P1, 192..383 -> P2)
    if (r < 3 * 24 * 64) {
        const int kt = r / (24 * 64), nt = (r / 64) % 24, l = r % 64;
        const int e = l & 15, kg = l >> 4;
        short8 v;
#pragma unroll
        for (int i = 0; i < 8; ++i) {
            const int k = kt * 32 + kg * 8 + i;
            const int col = nt * 16 + e;
            float val;
            if (col < 192) { const int row = (k < 64) ? k : k + 64;  val = mW1[row * 192 + col]; }
            else           { const int row = (k < 64) ? k + 64 : k + 96; val = mW1[row * 192 + (col - 192)]; }
            v[i] = f2bf(val);
        }
        *(short8*)&W1pk[r * 8] = v;
        return;
    }
    r -= 3 * 24 * 64;
    if (r < 6 * 4 * 64) {  // W2pk: msg-W2 [192,64], kt 0..5, nt 0..3
        const int kt = r / (4 * 64), nt = (r / 64) % 4, l = r % 64;
        const int e = l & 15, kg = l >> 4;
        short8 v;
#pragma unroll
        for (int i = 0; i < 8; ++i)
            v[i] = f2bf(mW2[(kt * 32 + kg * 8 + i) * 64 + nt * 16 + e]);
        *(short8*)&W2pk[r * 8] = v;
        return;
    }
    r -= 6 * 4 * 64;
    if (r < 4 * 12 * 64) {  // uW1pk: [128,192], kt 0..3, nt 0..11
        const int kt = r / (12 * 64), nt = (r / 64) % 12, l = r % 64;
        const int e = l & 15, kg = l >> 4;
        short8 v;
#pragma unroll
        for (int i = 0; i < 8; ++i)
            v[i] = f2bf(uW1[(kt * 32 + kg * 8 + i) * 192 + nt * 16 + e]);
        *(short8*)&uW1pk[r * 8] = v;
        return;
    }
    r -= 4 * 12 * 64;
    if (r < 6 * 8 * 64) {  // uW2pk: [192,128], kt 0..5, nt 0..7
        const int kt = r / (8 * 64), nt = (r / 64) % 8, l = r % 64;
        const int e = l & 15, kg = l >> 4;
        short8 v;
#pragma unroll
        for (int i = 0; i < 8; ++i)
            v[i] = f2bf(uW2[(kt * 32 + kg * 8 + i) * 128 + nt * 16 + e]);
        *(short8*)&uW2pk[r * 8] = v;
    }
}

// ---------------------------------------------------------------------------
// k_pre (MFMA): [P1|P2] = Xid[N,96] @ W1p[96,384] (+b1 on P1 half), bf16 out.
// Per wave: 16 nodes, 24 n-tiles, 3 k-tiles.
// ---------------------------------------------------------------------------
__global__ __launch_bounds__(256) void k_pre(const __hip_bfloat16* __restrict__ Xid,
                                             const __hip_bfloat16* __restrict__ W1pk,
                                             const float* __restrict__ b1,
                                             __hip_bfloat16* __restrict__ P1,
                                             __hip_bfloat16* __restrict__ P2) {
    const int t = threadIdx.x, w = t >> 6, l = t & 63;
    const int e = l & 15, kg = l >> 4;
    const int n0 = blockIdx.x * 64 + w * 16;

    short8 A[3];
#pragma unroll
    for (int kt = 0; kt < 3; ++kt)
        A[kt] = *(const short8*)&Xid[(n0 + e) * 96 + kt * 32 + kg * 8];

#pragma unroll
    for (int nt = 0; nt < 24; ++nt) {
        const float bv = (nt < 12) ? b1[nt * 16 + e] : 0.f;
        f32x4 acc = {bv, bv, bv, bv};
#pragma unroll
        for (int kt = 0; kt < 3; ++kt) {
            const short8 B = *(const short8*)&W1pk[((kt * 24 + nt) * 64 + l) * 8];
            acc = __builtin_amdgcn_mfma_f32_16x16x32_bf16(A[kt], B, acc, 0, 0, 0);
        }
#pragma unroll
        for (int r = 0; r < 4; ++r) {
            const int node = n0 + kg * 4 + r;
            if (node < N_NODES) {
                if (nt < 12) P1[node * 192 + nt * 16 + e] = __float2bfloat16(acc[r]);
                else         P2[node * 192 + (nt - 12) * 16 + e] = __float2bfloat16(acc[r]);
            }
        }
    }
}

// ---------------------------------------------------------------------------
// k_edge (MFMA): 16 edges/wave-iter. A = ReLU(P1[i]+P2[j]) built in A-frag
// layout; B = W2 frags staged in LDS (low VGPR -> higher occupancy).
// ---------------------------------------------------------------------------
__global__ __launch_bounds__(256) void k_edge(const int* __restrict__ ei,
                                              const float* __restrict__ ec,
                                              const __hip_bfloat16* __restrict__ P1,
                                              const __hip_bfloat16* __restrict__ P2,
                                              const __hip_bfloat16* __restrict__ W2pk,
                                              const float* __restrict__ b2,
                                              float* __restrict__ agg) {
    __shared__ uint4 w2s[6 * 4 * 64];  // 24576 B, fragment-ordered
    const int t = threadIdx.x;
    for (int v = t; v < 1536; v += 256) w2s[v] = ((const uint4*)W2pk)[v];
    __syncthreads();

    const int w = t >> 6, l = t & 63;
    const int e = l & 15, kg = l >> 4;
    float b2v[4];
#pragma unroll
    for (int n = 0; n < 4; ++n) b2v[n] = b2[n * 16 + e];

    const int nGroups = N_EDGES / 16;  // 50000
    const int wstride = gridDim.x * 4;

    for (int g = blockIdx.x * 4 + w; g < nGroups; g += wstride) {
        const int e0 = g * 16;
        const int jj = ei[e0 + e];
        const int ii = ei[N_EDGES + e0 + e];
        const __hip_bfloat16* r1 = P1 + (size_t)ii * 192 + kg * 8;
        const __hip_bfloat16* r2 = P2 + (size_t)jj * 192 + kg * 8;

        f32x4 acc0 = {0.f, 0.f, 0.f, 0.f};
        f32x4 acc1 = {0.f, 0.f, 0.f, 0.f};
        f32x4 acc2 = {0.f, 0.f, 0.f, 0.f};
        f32x4 acc3 = {0.f, 0.f, 0.f, 0.f};

#pragma unroll
        for (int tt = 0; tt < 6; ++tt) {
            union { uint4 q; unsigned u[4]; } A1, A2;
            A1.q = *(const uint4*)(r1 + tt * 32);
            A2.q = *(const uint4*)(r2 + tt * 32);
            short8 h;
#pragma unroll
            for (int p = 0; p < 4; ++p) {
                float s0 = bflo(A1.u[p]) + bflo(A2.u[p]);
                float s1 = bfhi(A1.u[p]) + bfhi(A2.u[p]);
                s0 = s0 > 0.f ? s0 : 0.f;
                s1 = s1 > 0.f ? s1 : 0.f;
                h[2 * p]     = f2bf(s0);
                h[2 * p + 1] = f2bf(s1);
            }
            acc0 = __builtin_amdgcn_mfma_f32_16x16x32_bf16(h, *(const short8*)&w2s[(tt * 4 + 0) * 64 + l], acc0, 0, 0, 0);
            acc1 = __builtin_amdgcn_mfma_f32_16x16x32_bf16(h, *(const short8*)&w2s[(tt * 4 + 1) * 64 + l], acc1, 0, 0, 0);
            acc2 = __builtin_amdgcn_mfma_f32_16x16x32_bf16(h, *(const short8*)&w2s[(tt * 4 + 2) * 64 + l], acc2, 0, 0, 0);
            acc3 = __builtin_amdgcn_mfma_f32_16x16x32_bf16(h, *(const short8*)&w2s[(tt * 4 + 3) * 64 + l], acc3, 0, 0, 0);
        }

        const float4 ecq = *(const float4*)(ec + e0 + kg * 4);
#pragma unroll
        for (int r = 0; r < 4; ++r) {
            const int edge = kg * 4 + r;
            const int it = __shfl(ii, edge);
            const float ecv = ((const float*)&ecq)[r];
            float v0 = (acc0[r] + b2v[0]) * ecv;
            float v1 = (acc1[r] + b2v[1]) * ecv;
            float v2 = (acc2[r] + b2v[2]) * ecv;
            float v3 = (acc3[r] + b2v[3]) * ecv;
            float* base = agg + (size_t)it * 64 + e;
            atomicAdd(base,      v0);
            atomicAdd(base + 16, v1);
            atomicAdd(base + 32, v2);
            atomicAdd(base + 48, v3);
        }
    }
}

// ---------------------------------------------------------------------------
// k_upd (fused MFMA): H = ReLU([x*nc|agg]@uW1+b1) staged in swizzled LDS,
// then out = H@uW2+b2. Per wave: 16 nodes.
// ---------------------------------------------------------------------------
__global__ __launch_bounds__(256) void k_upd(const __hip_bfloat16* __restrict__ Xid,
                                             const float* __restrict__ nc,
                                             const float* __restrict__ agg,
                                             const __hip_bfloat16* __restrict__ uW1pk,
                                             const float* __restrict__ ub1,
                                             const __hip_bfloat16* __restrict__ uW2pk,
                                             const float* __restrict__ ub2,
                                             float* __restrict__ out) {
    __shared__ char Hs[4][16 * 384];  // per-wave 16x192 bf16, XOR-swizzled
    const int t = threadIdx.x, w = t >> 6, l = t & 63;
    const int e = l & 15, kg = l >> 4;
    const int n0 = blockIdx.x * 64 + w * 16;
    const int nodeA = n0 + e;

    // A-fragments for GEMM1 (K=128: 0..63 x*nc, 64..127 agg)
    const float ncv = nc[nodeA < N_NODES ? nodeA : N_NODES - 1];
    short8 A[4];
#pragma unroll
    for (int kt = 0; kt < 2; ++kt) {
        const short8 xa = *(const short8*)&Xid[nodeA * 96 + kt * 32 + kg * 8];
        short8 o;
#pragma unroll
        for (int i = 0; i < 8; ++i) o[i] = f2bf(bf2f(xa[i]) * ncv);
        A[kt] = o;
    }
#pragma unroll
    for (int kt = 2; kt < 4; ++kt) {
        const float* ap = agg + (size_t)nodeA * 64 + (kt - 2) * 32 + kg * 8;
        const float4 a0 = *(const float4*)ap;
        const float4 a1 = *(const float4*)(ap + 4);
        short8 o;
        o[0] = f2bf(a0.x); o[1] = f2bf(a0.y); o[2] = f2bf(a0.z); o[3] = f2bf(a0.w);
        o[4] = f2bf(a1.x); o[5] = f2bf(a1.y); o[6] = f2bf(a1.z); o[7] = f2bf(a1.w);
        A[kt] = o;
    }

    // GEMM1 -> LDS (swizzled)
#pragma unroll
    for (int nt = 0; nt < 12; ++nt) {
        const float bv = ub1[nt * 16 + e];
        f32x4 acc = {bv, bv, bv, bv};
#pragma unroll
        for (int kt = 0; kt < 4; ++kt) {
            const short8 B = *(const short8*)&uW1pk[((kt * 12 + nt) * 64 + l) * 8];
            acc = __builtin_amdgcn_mfma_f32_16x16x32_bf16(A[kt], B, acc, 0, 0, 0);
        }
#pragma unroll
        for (int r = 0; r < 4; ++r) {
            const int hr = kg * 4 + r;
            const float v = acc[r] > 0.f ? acc[r] : 0.f;
            int byte = hr * 384 + (nt * 16 + e) * 2;
            byte ^= (hr & 7) << 4;
            *(__hip_bfloat16*)(&Hs[w][0] + byte) = __float2bfloat16(v);
        }
    }

    // GEMM2 A-fragments from LDS
    short8 A2[6];
#pragma unroll
    for (int kt = 0; kt < 6; ++kt) {
        int byte = e * 384 + kt * 64 + kg * 16;
        byte ^= (e & 7) << 4;
        A2[kt] = *(const short8*)(&Hs[w][0] + byte);
    }
#pragma unroll
    for (int nt = 0; nt < 8; ++nt) {
        const float bv = ub2[nt * 16 + e];
        f32x4 acc = {bv, bv, bv, bv};
#pragma unroll
        for (int kt = 0; kt < 6; ++kt) {
            const short8 B = *(const short8*)&uW2pk[((kt * 8 + nt) * 64 + l) * 8];
            acc = __builtin_amdgcn_mfma_f32_16x16x32_bf16(A2[kt], B, acc, 0, 0, 0);
        }
#pragma unroll
        for (int r = 0; r < 4; ++r) {
            const int node = n0 + kg * 4 + r;
            if (node < N_NODES) out[node * 128 + nt * 16 + e] = acc[r];
        }
    }
}

extern "C" void kernel_launch(void* const* d_in, const int* in_sizes, int n_in,
                              void* d_out, int out_size, void* d_ws, size_t ws_size,
                              hipStream_t stream) {
    const float* x   = (const float*)d_in[0];
    const int*   ei  = (const int*)d_in[1];
    const float* ncv = (const float*)d_in[2];
    const float* ecv = (const float*)d_in[3];
    const float* ids = (const float*)d_in[4];
    const float* mW1 = (const float*)d_in[6];
    const float* mb1 = (const float*)d_in[7];
    const float* mW2 = (const float*)d_in[8];
    const float* mb2 = (const float*)d_in[9];
    const float* uW1 = (const float*)d_in[10];
    const float* ub1 = (const float*)d_in[11];
    const float* uW2 = (const float*)d_in[12];
    const float* ub2 = (const float*)d_in[13];
    float* out = (float*)d_out;

    char* ws = (char*)d_ws;
    __hip_bfloat16* Xid  = (__hip_bfloat16*)ws;                 ws += (size_t)NPAD * 96 * 2;
    __hip_bfloat16* P1   = (__hip_bfloat16*)ws;                 ws += (size_t)NPAD * 192 * 2;
    __hip_bfloat16* P2   = (__hip_bfloat16*)ws;                 ws += (size_t)NPAD * 192 * 2;
    float*          agg  = (float*)ws;                          ws += (size_t)NPAD * 64 * 4;
    __hip_bfloat16* W1pk = (__hip_bfloat16*)ws;                 ws += 3 * 24 * 64 * 8 * 2;
    __hip_bfloat16* W2pk = (__hip_bfloat16*)ws;                 ws += 6 * 4 * 64 * 8 * 2;
    __hip_bfloat16* uW1pk= (__hip_bfloat16*)ws;                 ws += 4 * 12 * 64 * 8 * 2;
    __hip_bfloat16* uW2pk= (__hip_bfloat16*)ws;                 ws += 6 * 8 * 64 * 8 * 2;

    hipMemsetAsync(agg, 0, (size_t)NPAD * 64 * sizeof(float), stream);
    const int packWork = NPAD * 96 / 8 + 3 * 24 * 64 + 6 * 4 * 64 + 4 * 12 * 64 + 6 * 8 * 64;
    k_pack<<<(packWork + 255) / 256, 256, 0, stream>>>(x, ids, mW1, mW2, uW1, uW2,
                                                       Xid, W1pk, W2pk, uW1pk, uW2pk);
    k_pre<<<NPAD / 64, 256, 0, stream>>>(Xid, W1pk, mb1, P1, P2);
    k_edge<<<2048, 256, 0, stream>>>(ei, ecv, P1, P2, W2pk, mb2, agg);
    k_upd<<<NPAD / 64, 256, 0, stream>>>(Xid, ncv, agg, uW1pk, ub1, uW2pk, ub2, out);
}